// Round 16
// baseline (84.076 us; speedup 1.0000x reference)
//
#include <hip/hip_runtime.h>
#include <math.h>
#include <stdint.h>

#define NB 16
#define NN 50000
#define NC 8
#define ND 2
#define MAX_DET 300
#define NMS_T 0.5f
#define SCORE_T 0.05f
#define CAP 1024
#define CUTBIN 252        // s >= 0.984375 ; E[cnt]=781 +- 28
#define LBUF 128
#define NTILE32 32
#define STG 512           // greedy operates on top-512 (R12: sufficient on all bc)
#define NPI (NN * NC)
#define F4PB (NPI / 4 / NTILE32)

typedef unsigned long long u64;

__device__ __forceinline__ float neg_inf() { return -__builtin_inff(); }

// Bit-exact IoU > 0.5, division-free (R11-validated, absmax 0 since).
__device__ __forceinline__ bool iou_gt(float ax1, float ay1, float ax2, float ay2,
                                       float area_a,
                                       float bx1, float by1, float bx2, float by2,
                                       float area_b) {
    float x1 = fmaxf(ax1, bx1), y1 = fmaxf(ay1, by1);
    float x2 = fminf(ax2, bx2), y2 = fminf(ay2, by2);
    float inter = __fmul_rn(fmaxf(__fsub_rn(x2, x1), 0.0f),
                            fmaxf(__fsub_rn(y2, y1), 0.0f));
    float uni = __fsub_rn(__fadd_rn(area_a, area_b), inter);
    return inter > __fmul_rn(0.5f, fmaxf(uni, 1e-8f));
}

__device__ __forceinline__ u64 score_key(float s, int n) {
    unsigned u = __float_as_uint(s);
    u ^= (u & 0x80000000u) ? 0xFFFFFFFFu : 0x80000000u;
    return ((u64)u << 32) | (unsigned)(~(unsigned)n);
}

__device__ __forceinline__ u64 shfl_xor_u64(u64 v, int m) {
    unsigned lo = (unsigned)v, hi = (unsigned)(v >> 32);
    lo = __shfl_xor(lo, m, 64);
    hi = __shfl_xor(hi, m, 64);
    return ((u64)hi << 32) | lo;
}

// ---------------- K1: tiled compaction, no global atomics -----------------
__global__ __launch_bounds__(1024) void compact_kernel(
    const float* __restrict__ cls, int* __restrict__ tcnt_g,
    u64* __restrict__ cand)
{
    const int b = blockIdx.x >> 5, t32 = blockIdx.x & 31;
    const int tid = threadIdx.x;
    __shared__ u64 buf[8][LBUF];
    __shared__ int lcnt[8];
    if (tid < 8) lcnt[tid] = 0;
    __syncthreads();

    const float4* c4 = (const float4*)(cls + (size_t)b * NPI);
    const int f0 = t32 * F4PB, fend = f0 + F4PB;

    for (int f = f0 + tid; f < fend; f += 1024) {
        float4 v = c4[f];
        int cb = (f & 1) * 4;
        int n = f >> 1;
        float vv[4] = {v.x, v.y, v.z, v.w};
        #pragma unroll
        for (int k = 0; k < 4; ++k) {
            float s = vv[k];
            if (s > SCORE_T) {
                int bn = (int)(s * 256.0f); if (bn > 255) bn = 255;
                if (bn >= CUTBIN) {
                    int c = cb + k;
                    int pos = atomicAdd(&lcnt[c], 1);   // LDS only
                    if (pos < LBUF) buf[c][pos] = score_key(s, n);
                }
            }
        }
    }
    __syncthreads();
    {
        int c = tid >> 7, i = tid & (LBUF - 1);
        int m = lcnt[c];
        if (i < (m < LBUF ? m : LBUF))
            cand[(size_t)(((b * 8 + c) * NTILE32) + t32) * LBUF + i] = buf[c][i];
        if (i == 0) tcnt_g[(b * 8 + c) * NTILE32 + t32] = m;
    }
}

// ---------------- K2: gather + hybrid reg/LDS bitonic sort -> skeys --------
__global__ __launch_bounds__(512) void sort_kernel(
    const u64* __restrict__ cand, const int* __restrict__ tcnt_g,
    u64* __restrict__ skeys, int* __restrict__ meta)
{
    const int bc = blockIdx.x;
    const int tid = threadIdx.x;
    const int lane = tid & 63;
    __shared__ u64 keys[CAP];
    __shared__ int tcnt_s[NTILE32], toff_s[NTILE32];
    __shared__ int sh_total, sh_ovf;

    if (tid < 64) {
        int v = (lane < NTILE32) ? tcnt_g[bc * NTILE32 + lane] : 0;
        int incl = v;
        #pragma unroll
        for (int d = 1; d < 32; d <<= 1) {
            int o = __shfl_up(incl, d, 64);
            if (lane >= d) incl += o;
        }
        if (lane < NTILE32) { tcnt_s[lane] = v; toff_s[lane] = incl - v; }
        u64 ov = __ballot(lane < NTILE32 && v > LBUF);
        if (lane == 31) { sh_total = incl; sh_ovf = (ov != 0); }
    }
    __syncthreads();
    const int cnt = sh_total;
    const bool full_fb = sh_ovf || (cnt > CAP);
    if (full_fb) {
        if (tid == 0) meta[bc] = -1;
        return;
    }
    if (tid == 0) meta[bc] = cnt;

    for (int i = tid; i < CAP; i += 512) keys[i] = 0ull;
    __syncthreads();
    for (int s = tid; s < NTILE32 * LBUF; s += 512) {
        int t = s >> 7, i = s & (LBUF - 1);
        if (i < tcnt_s[t])
            keys[toff_s[t] + i] = cand[(size_t)(bc * NTILE32 + t) * LBUF + i];
    }
    __syncthreads();

    const int p0 = (tid >> 6) * 128 + lane, p1 = p0 + 64;
    u64 v0 = keys[p0], v1 = keys[p1];
    #pragma unroll
    for (int k = 2; k <= 128; k <<= 1) {
        #pragma unroll
        for (int j = k >> 1; j > 0; j >>= 1) {
            if (j == 64) {
                bool dir = ((p0 & k) == 0);
                if ((v0 < v1) == dir) { u64 t = v0; v0 = v1; v1 = t; }
            } else {
                bool lower = ((lane & j) == 0);
                bool dir0 = ((p0 & k) == 0);
                bool dir1 = ((p1 & k) == 0);   // differs at k=64
                u64 o0 = shfl_xor_u64(v0, j);
                u64 mx0 = v0 > o0 ? v0 : o0, mn0 = v0 > o0 ? o0 : v0;
                v0 = (lower == dir0) ? mx0 : mn0;
                u64 o1 = shfl_xor_u64(v1, j);
                u64 mx1 = v1 > o1 ? v1 : o1, mn1 = v1 > o1 ? o1 : v1;
                v1 = (lower == dir1) ? mx1 : mn1;
            }
        }
    }
    __syncthreads();
    for (int k = 256; k <= CAP; k <<= 1) {
        keys[p0] = v0; keys[p1] = v1;
        __syncthreads();
        for (int j = k >> 1; j >= 128; j >>= 1) {
            int p = tid;
            int i = 2 * p - (p & (j - 1));
            int ix = i + j;
            bool dir = ((i & k) == 0);
            u64 a = keys[i], b2 = keys[ix];
            if ((a < b2) == dir) { keys[i] = b2; keys[ix] = a; }
            __syncthreads();
        }
        v0 = keys[p0]; v1 = keys[p1];
        {
            bool dir = ((p0 & k) == 0);
            if ((v0 < v1) == dir) { u64 t = v0; v0 = v1; v1 = t; }
        }
        #pragma unroll
        for (int j = 32; j > 0; j >>= 1) {   // k>=256: (p1&k)==(p0&k)
            bool lower = ((lane & j) == 0);
            bool dir = ((p0 & k) == 0);
            u64 o0 = shfl_xor_u64(v0, j);
            u64 mx0 = v0 > o0 ? v0 : o0, mn0 = v0 > o0 ? o0 : v0;
            v0 = (lower == dir) ? mx0 : mn0;
            u64 o1 = shfl_xor_u64(v1, j);
            u64 mx1 = v1 > o1 ? v1 : o1, mn1 = v1 > o1 ? o1 : v1;
            v1 = (lower == dir) ? mx1 : mn1;
        }
        __syncthreads();
    }
    skeys[(size_t)bc * CAP + p0] = v0;
    skeys[(size_t)bc * CAP + p1] = v1;
}

// ---------------- K3: 512x512 lower-triangle matrix (full GPU) ------------
// grid = NB*NC*4; block (bc,q) computes rows r with r%4==q.
__global__ __launch_bounds__(128) void matrix_kernel(
    const float* __restrict__ boxes, const u64* __restrict__ skeys,
    const int* __restrict__ meta, u64* __restrict__ Mg)
{
    const int bc = blockIdx.x >> 2, q = blockIdx.x & 3;
    const int b = bc >> 3;
    const int tid = threadIdx.x;
    const int mcnt = meta[bc];
    if (mcnt < 0) return;                      // full-fallback path
    const int inSet = mcnt < CAP ? mcnt : CAP;
    const int stage = inSet < STG ? inSet : STG;

    __shared__ float4 sbox[STG];
    __shared__ float  sarea[STG];
    const float4* bx4 = (const float4*)(boxes + (size_t)b * NN * 4);
    const u64* sk = skeys + (size_t)bc * CAP;

    for (int i = tid; i < stage; i += 128) {
        u64 key = sk[i];
        int idx = (int)(~(unsigned)key);
        float4 bb = bx4[idx];
        sbox[i] = bb;
        sarea[i] = __fmul_rn(__fsub_rn(bb.z, bb.x), __fsub_rn(bb.w, bb.y));
    }
    __syncthreads();

    int r = q + 4 * tid;                       // tid<128 -> r<512
    if (r < stage) {
        float4 B = sbox[r];
        float Barea = sarea[r];
        u64* row = Mg + ((size_t)bc * STG + r) * 8;
        #pragma unroll
        for (int h = 0; h < 8; ++h) {
            u64 bits = 0;
            int j0 = h * 64;
            int jlim = r - j0;
            if (jlim > 64) jlim = 64;
            int jj = 0;
            for (; jj + 3 < jlim; jj += 4) {
                int j = j0 + jj;
                float4 A0 = sbox[j];     float r0 = sarea[j];
                float4 A1 = sbox[j + 1]; float r1 = sarea[j + 1];
                float4 A2 = sbox[j + 2]; float r2 = sarea[j + 2];
                float4 A3 = sbox[j + 3]; float r3 = sarea[j + 3];
                if (iou_gt(A0.x,A0.y,A0.z,A0.w,r0,B.x,B.y,B.z,B.w,Barea)) bits |= 1ull << jj;
                if (iou_gt(A1.x,A1.y,A1.z,A1.w,r1,B.x,B.y,B.z,B.w,Barea)) bits |= 1ull << (jj+1);
                if (iou_gt(A2.x,A2.y,A2.z,A2.w,r2,B.x,B.y,B.z,B.w,Barea)) bits |= 1ull << (jj+2);
                if (iou_gt(A3.x,A3.y,A3.z,A3.w,r3,B.x,B.y,B.z,B.w,Barea)) bits |= 1ull << (jj+3);
            }
            for (; jj < jlim; ++jj) {
                int j = j0 + jj;
                float4 A = sbox[j];
                if (iou_gt(A.x,A.y,A.z,A.w,sarea[j],B.x,B.y,B.z,B.w,Barea))
                    bits |= 1ull << jj;
            }
            row[h] = bits;                     // zero beyond triangle
        }
    }
}

// ---------------- K4: register fixpoint resolve + write (+ fallbacks) -----
__global__ __launch_bounds__(512) void resolve_kernel(
    const float* __restrict__ boxes, const float* __restrict__ cls,
    const u64* __restrict__ skeys, const int* __restrict__ meta,
    const u64* __restrict__ Mg,
    int* __restrict__ sel_idx, float* __restrict__ sel_score)
{
    const int bc = blockIdx.x;
    const int b = bc >> 3, c = bc & 7;
    const int tid = threadIdx.x;
    const int lane = tid & 63;
    const float4* bx4 = (const float4*)(boxes + (size_t)b * NN * 4);
    const float* sr = cls + (size_t)b * NN * NC + c;      // fallback only
    const u64* sk = skeys + (size_t)bc * CAP;
    int* si = sel_idx + bc * MAX_DET;
    float* ss = sel_score + bc * MAX_DET;

    __shared__ u64 accs_s[8];
    __shared__ float4 abox[MAX_DET];
    __shared__ float aarea[MAX_DET];
    __shared__ unsigned bm[(NN + 31) / 32];
    __shared__ float rv[512];
    __shared__ int   ri[512];
    __shared__ float sboxsh[5];

    const int mcnt = meta[bc];
    const bool full_fb = (mcnt < 0);
    const int inSet = full_fb ? 0 : (mcnt < CAP ? mcnt : CAP);
    const int stage = inSet < STG ? inSet : STG;

    int n_acc = 0;
    if (!full_fb) {
        if (tid < 64) {
            u64 Mr[8][8];
            unsigned pe[8];
            bool acc[8];
            #pragma unroll
            for (int cg = 0; cg < 8; ++cg) {
                int i = cg * 64 + lane;
                pe[cg] = (i < stage) ? 0u : 1u;
                const u64* row = Mg + ((size_t)bc * STG + i) * 8;
                #pragma unroll
                for (int w = 0; w < 8; ++w) Mr[cg][w] = row[w];
                acc[cg] = (pe[cg] == 0);
            }
            u64 a[8];
            #pragma unroll
            for (int h = 0; h < 8; ++h) a[h] = __ballot(acc[h]);
            for (int it = 0; it < STG + 8; ++it) {
                #pragma unroll
                for (int cg = 0; cg < 8; ++cg) {
                    u64 sup = 0;
                    #pragma unroll
                    for (int h = 0; h < 8; ++h) sup |= Mr[cg][h] & a[h];
                    acc[cg] = (pe[cg] == 0) && (sup == 0ull);
                }
                u64 nb[8]; bool same = true;
                #pragma unroll
                for (int h = 0; h < 8; ++h) {
                    nb[h] = __ballot(acc[h]);
                    same = same && (nb[h] == a[h]);
                    a[h] = nb[h];
                }
                if (same) break;
            }
            if (lane == 0) {
                #pragma unroll
                for (int h = 0; h < 8; ++h) accs_s[h] = a[h];
            }
        }
        __syncthreads();

        {
            u64 a[8]; int tot = 0;
            #pragma unroll
            for (int h = 0; h < 8; ++h) { a[h] = accs_s[h]; tot += __popcll(a[h]); }
            n_acc = tot < MAX_DET ? tot : MAX_DET;
            if (tid < stage) {
                int cg = tid >> 6, o = tid & 63;
                if ((a[cg] >> o) & 1ull) {
                    int rank = 0;
                    for (int h = 0; h < cg; ++h) rank += __popcll(a[h]);
                    rank += __popcll(a[cg] & ((o == 0) ? 0ull : ((1ull << o) - 1ull)));
                    if (rank < MAX_DET) {
                        u64 key = sk[tid];
                        int idx = (int)(~(unsigned)key);
                        unsigned u = (unsigned)(key >> 32);
                        unsigned uo = (u & 0x80000000u) ? (u ^ 0x80000000u) : (~u);
                        si[rank] = idx; ss[rank] = __uint_as_float(uo);
                    }
                }
            }
        }
        __syncthreads();
    }

    const bool part_fb = (!full_fb) && (n_acc < MAX_DET);

    if (full_fb || part_fb) {
        // gather accepted boxes for the continuation
        if (part_fb) {
            for (int t = tid; t < n_acc; t += 512) {
                int n = si[t];
                float4 bb = bx4[n];
                abox[t] = bb;
                aarea[t] = __fmul_rn(__fsub_rn(bb.z, bb.x), __fsub_rn(bb.w, bb.y));
            }
        }
        __syncthreads();
        const int BMW = (NN + 31) / 32;
        for (int i = tid; i < BMW; i += 512) bm[i] = 0u;
        __syncthreads();
        if (full_fb) {
            n_acc = 0;
        } else {
            for (int n = tid; n < NN; n += 512) {
                float4 bbn = bx4[n];
                float nb_area = __fmul_rn(__fsub_rn(bbn.z, bbn.x), __fsub_rn(bbn.w, bbn.y));
                int s = 0;
                for (int t = 0; t < n_acc; ++t) {
                    float4 A = abox[t];
                    if (iou_gt(A.x, A.y, A.z, A.w, aarea[t],
                               bbn.x, bbn.y, bbn.z, bbn.w, nb_area)) s = 1;
                }
                if (s) atomicOr(&bm[n >> 5], 1u << (n & 31));
            }
        }
        __syncthreads();

        for (int k = n_acc; k < MAX_DET; ++k) {
            float bv = neg_inf(); int bi = 0x7fffffff;
            for (int n = tid; n < NN; n += 512) {
                if (!((bm[n >> 5] >> (n & 31)) & 1u)) {
                    float v = sr[(size_t)n * NC];
                    if (v > SCORE_T && v > bv) { bv = v; bi = n; }
                }
            }
            rv[tid] = bv; ri[tid] = bi;
            __syncthreads();
            for (int s = 256; s > 0; s >>= 1) {
                if (tid < s) {
                    float ov = rv[tid + s]; int oi = ri[tid + s];
                    if (ov > rv[tid] || (ov == rv[tid] && oi < ri[tid])) { rv[tid] = ov; ri[tid] = oi; }
                }
                __syncthreads();
            }
            float mval = rv[0]; int midx = ri[0];
            if (mval == neg_inf()) {
                for (int kk = k + tid; kk < MAX_DET; kk += 512) { si[kk] = 0; ss[kk] = neg_inf(); }
                break;
            }
            if (tid == 0) {
                si[k] = midx; ss[k] = mval;
                float4 sb = bx4[midx];
                sboxsh[0] = sb.x; sboxsh[1] = sb.y; sboxsh[2] = sb.z; sboxsh[3] = sb.w;
                sboxsh[4] = __fmul_rn(__fsub_rn(sb.z, sb.x), __fsub_rn(sb.w, sb.y));
            }
            __syncthreads();
            float ax1 = sboxsh[0], ay1 = sboxsh[1], ax2 = sboxsh[2], ay2 = sboxsh[3];
            float area_a = sboxsh[4];
            for (int n = tid; n < NN; n += 512) {
                float4 bbn = bx4[n];
                float nb_area = __fmul_rn(__fsub_rn(bbn.z, bbn.x), __fsub_rn(bbn.w, bbn.y));
                if (iou_gt(ax1, ay1, ax2, ay2, area_a,
                           bbn.x, bbn.y, bbn.z, bbn.w, nb_area))
                    atomicOr(&bm[n >> 5], 1u << (n & 31));
            }
            __syncthreads();
        }
    }
    // n_acc >= 300 without fallback: all 300 slots written above.
}

// ---------------- K5: top-300 via interleaved 8-way rank-selection --------
__global__ __launch_bounds__(1024) void topk_kernel(
    const float* __restrict__ boxes, const float* __restrict__ other,
    const int* __restrict__ sel_idx, const float* __restrict__ sel_score,
    float* __restrict__ out)
{
    const int b = blockIdx.x;
    const int tid = threadIdx.x;
    const int NCAND = NC * MAX_DET;        // 2400
    __shared__ u64 lists[NC][MAX_DET];

    for (int i = tid; i < NCAND; i += 1024) {
        float v = sel_score[b * NCAND + i];
        unsigned u = __float_as_uint(v);
        u ^= (u & 0x80000000u) ? 0xFFFFFFFFu : 0x80000000u;
        lists[i / MAX_DET][i % MAX_DET] = ((u64)u << 32) | (unsigned)(~(unsigned)i);
    }
    __syncthreads();

    const float4* bx4 = (const float4*)(boxes + (size_t)b * NN * 4);
    const float*  ot  = other + (size_t)b * NN * ND;
    float* ob = out;
    float* os = out + NB * MAX_DET * 4;
    float* ol = os + NB * MAX_DET;
    float* oo = ol + NB * MAX_DET;

    for (int i = tid; i < NCAND; i += 1024) {
        int cown = i / MAX_DET, slot = i - cown * MAX_DET;
        u64 K = lists[cown][slot];
        int rank = slot;
        int pos[NC], len[NC];
        #pragma unroll
        for (int c2 = 0; c2 < NC; ++c2) {
            pos[c2] = 0;
            len[c2] = (c2 == cown) ? 0 : MAX_DET;
        }
        for (int step = 0; step < 10; ++step) {
            #pragma unroll
            for (int c2 = 0; c2 < NC; ++c2) {
                if (len[c2] > 0) {
                    int half = len[c2] >> 1;
                    bool go = lists[c2][pos[c2] + half] > K;
                    pos[c2] = go ? pos[c2] + half + 1 : pos[c2];
                    len[c2] = go ? len[c2] - half - 1 : half;
                }
            }
        }
        #pragma unroll
        for (int c2 = 0; c2 < NC; ++c2) rank += pos[c2];

        if (rank < MAX_DET) {
            unsigned u = (unsigned)(K >> 32);
            unsigned uo = (u & 0x80000000u) ? (u ^ 0x80000000u) : (u ^ 0xFFFFFFFFu);
            float score = __uint_as_float(uo);
            bool valid = isfinite(score);
            float b0=-1.f,b1=-1.f,b2=-1.f,b3=-1.f,scv=-1.f,lab=-1.f,o0=-1.f,o1=-1.f;
            if (valid) {
                int n = sel_idx[b * NCAND + i];
                float4 bb = bx4[n];
                b0 = bb.x; b1 = bb.y; b2 = bb.z; b3 = bb.w;
                scv = score; lab = (float)cown;
                o0 = ot[n * ND + 0]; o1 = ot[n * ND + 1];
            }
            int base = b * MAX_DET + rank;
            ob[base * 4 + 0] = b0; ob[base * 4 + 1] = b1;
            ob[base * 4 + 2] = b2; ob[base * 4 + 3] = b3;
            os[base] = scv; ol[base] = lab;
            oo[base * 2 + 0] = o0; oo[base * 2 + 1] = o1;
        }
    }
}

extern "C" void kernel_launch(void* const* d_in, const int* in_sizes, int n_in,
                              void* d_out, int out_size, void* d_ws, size_t ws_size,
                              hipStream_t stream) {
    const float* boxes = (const float*)d_in[0];
    const float* cls   = (const float*)d_in[1];
    const float* other = (const float*)d_in[2];
    float* out = (float*)d_out;

    // ws: tcnt[4096] i32 | meta[128] i32 | pad | cand[128*4096] u64
    //   | skeys[128*1024] u64 | Mg[128*512*8] u64 | sel_idx | sel_score
    int* tcnt_g = (int*)d_ws;
    int* meta   = tcnt_g + NB * NC * NTILE32;
    u64* cand   = (u64*)(meta + 128);                       // 16896B -> 8-aligned
    u64* skeys  = cand + (size_t)NB * NC * NTILE32 * LBUF;  // +4MB
    u64* Mg     = skeys + (size_t)NB * NC * CAP;            // +1MB
    int* sel_idx = (int*)(Mg + (size_t)NB * NC * STG * 8);  // +4MB
    float* sel_score = (float*)(sel_idx + NB * NC * MAX_DET);

    compact_kernel<<<NB * NTILE32, 1024, 0, stream>>>(cls, tcnt_g, cand);
    sort_kernel<<<NB * NC, 512, 0, stream>>>(cand, tcnt_g, skeys, meta);
    matrix_kernel<<<NB * NC * 4, 128, 0, stream>>>(boxes, skeys, meta, Mg);
    resolve_kernel<<<NB * NC, 512, 0, stream>>>(boxes, cls, skeys, meta, Mg,
                                                sel_idx, sel_score);
    topk_kernel<<<NB, 1024, 0, stream>>>(boxes, other, sel_idx, sel_score, out);
}

// Round 18
// 68.312 us; speedup vs baseline: 1.2308x; 1.2308x over previous
//
#include <hip/hip_runtime.h>
#include <math.h>
#include <stdint.h>

#define NB 16
#define NN 50000
#define NC 8
#define ND 2
#define MAX_DET 300
#define NMS_T 0.5f
#define SCORE_T 0.05f
#define CAP 1024
#define CUTBIN 252        // s >= 0.984375 ; E[cnt]=781 +- 28
#define LBUF 128
#define NTILE32 32
#define STG 512
#define NT 1024
#define NPI (NN * NC)
#define F4PB (NPI / 4 / NTILE32)

typedef unsigned long long u64;

__device__ __forceinline__ float neg_inf() { return -__builtin_inff(); }

// Bit-exact IoU > 0.5, division-free (R11-validated, absmax 0 since).
__device__ __forceinline__ bool iou_gt(float ax1, float ay1, float ax2, float ay2,
                                       float area_a,
                                       float bx1, float by1, float bx2, float by2,
                                       float area_b) {
    float x1 = fmaxf(ax1, bx1), y1 = fmaxf(ay1, by1);
    float x2 = fminf(ax2, bx2), y2 = fminf(ay2, by2);
    float inter = __fmul_rn(fmaxf(__fsub_rn(x2, x1), 0.0f),
                            fmaxf(__fsub_rn(y2, y1), 0.0f));
    float uni = __fsub_rn(__fadd_rn(area_a, area_b), inter);
    return inter > __fmul_rn(0.5f, fmaxf(uni, 1e-8f));
}

__device__ __forceinline__ u64 score_key(float s, int n) {
    unsigned u = __float_as_uint(s);
    u ^= (u & 0x80000000u) ? 0xFFFFFFFFu : 0x80000000u;
    return ((u64)u << 32) | (unsigned)(~(unsigned)n);
}

__device__ __forceinline__ u64 shfl_xor_u64(u64 v, int m) {
    unsigned lo = (unsigned)v, hi = (unsigned)(v >> 32);
    lo = __shfl_xor(lo, m, 64);
    hi = __shfl_xor(hi, m, 64);
    return ((u64)hi << 32) | lo;
}

// ---------------- K1: tiled compaction, no global atomics -----------------
__global__ __launch_bounds__(1024) void compact_kernel(
    const float* __restrict__ cls, int* __restrict__ tcnt_g,
    u64* __restrict__ cand)
{
    const int b = blockIdx.x >> 5, t32 = blockIdx.x & 31;
    const int tid = threadIdx.x;
    __shared__ u64 buf[8][LBUF];
    __shared__ int lcnt[8];
    if (tid < 8) lcnt[tid] = 0;
    __syncthreads();

    const float4* c4 = (const float4*)(cls + (size_t)b * NPI);
    const int f0 = t32 * F4PB, fend = f0 + F4PB;

    for (int f = f0 + tid; f < fend; f += 1024) {
        float4 v = c4[f];
        int cb = (f & 1) * 4;
        int n = f >> 1;
        float vv[4] = {v.x, v.y, v.z, v.w};
        #pragma unroll
        for (int k = 0; k < 4; ++k) {
            float s = vv[k];
            if (s > SCORE_T) {
                int bn = (int)(s * 256.0f); if (bn > 255) bn = 255;
                if (bn >= CUTBIN) {
                    int c = cb + k;
                    int pos = atomicAdd(&lcnt[c], 1);   // LDS only
                    if (pos < LBUF) buf[c][pos] = score_key(s, n);
                }
            }
        }
    }
    __syncthreads();
    {
        int c = tid >> 7, i = tid & (LBUF - 1);
        int m = lcnt[c];
        if (i < (m < LBUF ? m : LBUF))
            cand[(size_t)(((b * 8 + c) * NTILE32) + t32) * LBUF + i] = buf[c][i];
        if (i == 0) tcnt_g[(b * 8 + c) * NTILE32 + t32] = m;
    }
}

// ---------------- K2: fused gather + sort + 512 matrix + fixpoint ----------
__global__ __launch_bounds__(NT) void nms_fused(
    const float* __restrict__ boxes, const float* __restrict__ cls,
    const u64* __restrict__ cand, const int* __restrict__ tcnt_g,
    int* __restrict__ sel_idx, float* __restrict__ sel_score)
{
    const int bc = blockIdx.x;
    const int b = bc >> 3, c = bc & 7;
    const int tid = threadIdx.x;
    const int lane = tid & 63;
    const float4* bx4 = (const float4*)(boxes + (size_t)b * NN * 4);
    const float* sr = cls + (size_t)b * NN * NC + c;   // fallback only
    int* si = sel_idx + bc * MAX_DET;
    float* ss = sel_score + bc * MAX_DET;

    __shared__ u64 keys[CAP];                    // 8 KB
    __shared__ int tcnt_s[NTILE32], toff_s[NTILE32];
    __shared__ int sh_total, sh_ovf;
    __shared__ float4 sbox[STG];                 // 8 KB
    __shared__ float  sarea[STG];                // 2 KB
    __shared__ int    sidx[STG];                 // 2 KB
    __shared__ float  sscore[STG];               // 2 KB
    __shared__ __align__(16) char regM[32768];   // M8[8][512] | {bm, rv, ri}
    __shared__ u64 accs_s[8];
    __shared__ float4 abox[MAX_DET];
    __shared__ float aarea[MAX_DET];
    __shared__ float sboxsh[5];

    u64 (*M8)[STG] = (u64(*)[STG])regM;          // word-major: M8[h][i]
    unsigned* bm = (unsigned*)regM;              // fallback bitmask (6252 B)
    float* rv = (float*)(regM + 6656);           // [1024] 4 KB
    int*   ri = (int*)(regM + 10752);            // [1024] 4 KB

    // ---- tile-count scan (wave 0) ----
    if (tid < 64) {
        int v = (lane < NTILE32) ? tcnt_g[bc * NTILE32 + lane] : 0;
        int incl = v;
        #pragma unroll
        for (int d = 1; d < 32; d <<= 1) {
            int o = __shfl_up(incl, d, 64);
            if (lane >= d) incl += o;
        }
        if (lane < NTILE32) { tcnt_s[lane] = v; toff_s[lane] = incl - v; }
        u64 ov = __ballot(lane < NTILE32 && v > LBUF);
        if (lane == 31) { sh_total = incl; sh_ovf = (ov != 0); }
    }
    __syncthreads();
    const int cnt = sh_total;
    const bool full_fb = sh_ovf || (cnt > CAP);
    const int inSet = cnt < CAP ? cnt : CAP;
    const int stage = inSet < STG ? inSet : STG;

    int n_acc = 0;
    if (!full_fb) {
        // ---- zero + flat gather into keys ----
        for (int i = tid; i < CAP; i += NT) keys[i] = 0ull;
        __syncthreads();
        for (int s = tid; s < NTILE32 * LBUF; s += NT) {
            int t = s >> 7, i = s & (LBUF - 1);
            if (i < tcnt_s[t])
                keys[toff_s[t] + i] = cand[(size_t)(bc * NTILE32 + t) * LBUF + i];
        }
        __syncthreads();

        // ===== hybrid reg/LDS bitonic sort (threads 0-511, R14-verified) ====
        const int p0 = (tid >> 6) * 128 + lane, p1 = p0 + 64;
        u64 v0 = 0, v1 = 0;
        if (tid < 512) {
            v0 = keys[p0]; v1 = keys[p1];
            #pragma unroll
            for (int k = 2; k <= 128; k <<= 1) {
                #pragma unroll
                for (int j = k >> 1; j > 0; j >>= 1) {
                    if (j == 64) {
                        bool dir = ((p0 & k) == 0);
                        if ((v0 < v1) == dir) { u64 t = v0; v0 = v1; v1 = t; }
                    } else {
                        bool lower = ((lane & j) == 0);
                        bool dir0 = ((p0 & k) == 0);
                        bool dir1 = ((p1 & k) == 0);   // differs at k=64
                        u64 o0 = shfl_xor_u64(v0, j);
                        u64 mx0 = v0 > o0 ? v0 : o0, mn0 = v0 > o0 ? o0 : v0;
                        v0 = (lower == dir0) ? mx0 : mn0;
                        u64 o1 = shfl_xor_u64(v1, j);
                        u64 mx1 = v1 > o1 ? v1 : o1, mn1 = v1 > o1 ? o1 : v1;
                        v1 = (lower == dir1) ? mx1 : mn1;
                    }
                }
            }
        }
        __syncthreads();
        for (int k = 256; k <= CAP; k <<= 1) {
            if (tid < 512) { keys[p0] = v0; keys[p1] = v1; }
            __syncthreads();
            for (int j = k >> 1; j >= 128; j >>= 1) {
                if (tid < 512) {
                    int p = tid;
                    int i = 2 * p - (p & (j - 1));
                    int ix = i + j;
                    bool dir = ((i & k) == 0);
                    u64 a = keys[i], b2 = keys[ix];
                    if ((a < b2) == dir) { keys[i] = b2; keys[ix] = a; }
                }
                __syncthreads();
            }
            if (tid < 512) {
                v0 = keys[p0]; v1 = keys[p1];
                {
                    bool dir = ((p0 & k) == 0);
                    if ((v0 < v1) == dir) { u64 t = v0; v0 = v1; v1 = t; }
                }
                #pragma unroll
                for (int j = 32; j > 0; j >>= 1) {   // k>=256: (p1&k)==(p0&k)
                    bool lower = ((lane & j) == 0);
                    bool dir = ((p0 & k) == 0);
                    u64 o0 = shfl_xor_u64(v0, j);
                    u64 mx0 = v0 > o0 ? v0 : o0, mn0 = v0 > o0 ? o0 : v0;
                    v0 = (lower == dir) ? mx0 : mn0;
                    u64 o1 = shfl_xor_u64(v1, j);
                    u64 mx1 = v1 > o1 ? v1 : o1, mn1 = v1 > o1 ? o1 : v1;
                    v1 = (lower == dir) ? mx1 : mn1;
                }
            }
            __syncthreads();
        }
        if (tid < 512) { keys[p0] = v0; keys[p1] = v1; }
        __syncthreads();

        // ===== stage top-512 =====
        if (tid < 512 && tid < stage) {
            u64 key = keys[tid];
            int idx = (int)(~(unsigned)key);
            unsigned u = (unsigned)(key >> 32);
            unsigned uo = (u & 0x80000000u) ? (u ^ 0x80000000u) : (~u);
            float4 bb = bx4[idx];
            sbox[tid] = bb;
            sarea[tid] = __fmul_rn(__fsub_rn(bb.z, bb.x), __fsub_rn(bb.w, bb.y));
            sidx[tid] = idx; sscore[tid] = __uint_as_float(uo);
        }
        __syncthreads();

        // ===== single matrix phase: 2 threads per row, word-aligned split ===
        {
            int r = tid >> 1, h2 = tid & 1;
            if (r < stage) {
                int mid = ((r >> 1) + 32) & ~63;       // 64-aligned split point
                int jlo = h2 ? mid : 0;
                int jhi = h2 ? r : (mid < r ? mid : r);
                int w0 = h2 ? (mid >> 6) : 0;
                int w1 = h2 ? 8 : (mid >> 6);          // [w0, w1) words owned
                float4 B = sbox[r];
                float Barea = sarea[r];
                for (int w = w0; w < w1; ++w) {
                    u64 bits = 0;
                    int js = jlo > (w << 6) ? jlo : (w << 6);
                    int je = jhi < ((w + 1) << 6) ? jhi : ((w + 1) << 6);
                    int jj = js;
                    for (; jj + 3 < je; jj += 4) {
                        float4 A0 = sbox[jj];     float r0 = sarea[jj];
                        float4 A1 = sbox[jj + 1]; float r1 = sarea[jj + 1];
                        float4 A2 = sbox[jj + 2]; float r2 = sarea[jj + 2];
                        float4 A3 = sbox[jj + 3]; float r3 = sarea[jj + 3];
                        if (iou_gt(A0.x,A0.y,A0.z,A0.w,r0,B.x,B.y,B.z,B.w,Barea)) bits |= 1ull << (jj - (w<<6));
                        if (iou_gt(A1.x,A1.y,A1.z,A1.w,r1,B.x,B.y,B.z,B.w,Barea)) bits |= 1ull << (jj+1 - (w<<6));
                        if (iou_gt(A2.x,A2.y,A2.z,A2.w,r2,B.x,B.y,B.z,B.w,Barea)) bits |= 1ull << (jj+2 - (w<<6));
                        if (iou_gt(A3.x,A3.y,A3.z,A3.w,r3,B.x,B.y,B.z,B.w,Barea)) bits |= 1ull << (jj+3 - (w<<6));
                    }
                    for (; jj < je; ++jj) {
                        float4 A = sbox[jj];
                        if (iou_gt(A.x,A.y,A.z,A.w,sarea[jj],B.x,B.y,B.z,B.w,Barea))
                            bits |= 1ull << (jj - (w<<6));
                    }
                    M8[w][r] = bits;
                }
            }
        }
        __syncthreads();

        // ===== fixpoint resolve (wave 0; M from LDS; R16-verified scheme) ===
        if (tid < 64) {
            unsigned pe[8]; bool acc[8];
            #pragma unroll
            for (int cg = 0; cg < 8; ++cg) {
                int i = cg * 64 + lane;
                pe[cg] = (i < stage) ? 0u : 1u;
                acc[cg] = (pe[cg] == 0);
            }
            u64 a[8];
            #pragma unroll
            for (int h = 0; h < 8; ++h) a[h] = __ballot(acc[h]);
            for (int it = 0; it < STG + 8; ++it) {
                #pragma unroll
                for (int cg = 0; cg < 8; ++cg) {
                    int i = cg * 64 + lane;
                    u64 sup = 0;
                    #pragma unroll
                    for (int h = 0; h < 8; ++h) sup |= M8[h][i] & a[h];
                    acc[cg] = (pe[cg] == 0) && (sup == 0ull);
                }
                u64 nb[8]; bool same = true;
                #pragma unroll
                for (int h = 0; h < 8; ++h) {
                    nb[h] = __ballot(acc[h]);
                    same = same && (nb[h] == a[h]);
                    a[h] = nb[h];
                }
                if (same) break;
            }
            if (lane == 0) {
                #pragma unroll
                for (int h = 0; h < 8; ++h) accs_s[h] = a[h];
            }
        }
        __syncthreads();

        // ===== rank + write (cap 300); fill abox for potential fallback =====
        {
            u64 a[8]; int tot = 0;
            #pragma unroll
            for (int h = 0; h < 8; ++h) { a[h] = accs_s[h]; tot += __popcll(a[h]); }
            n_acc = tot < MAX_DET ? tot : MAX_DET;
            if (tid < 512 && tid < stage) {
                int cg = tid >> 6, o = tid & 63;
                if ((a[cg] >> o) & 1ull) {
                    int rank = 0;
                    for (int h = 0; h < cg; ++h) rank += __popcll(a[h]);
                    rank += __popcll(a[cg] & ((o == 0) ? 0ull : ((1ull << o) - 1ull)));
                    if (rank < MAX_DET) {
                        si[rank] = sidx[tid]; ss[rank] = sscore[tid];
                        abox[rank] = sbox[tid]; aarea[rank] = sarea[tid];
                    }
                }
            }
        }
        __syncthreads();
    }

    const bool part_fb = (!full_fb) && (n_acc < MAX_DET);

    if (full_fb || part_fb) {
        // ======== exact fallback: bitmask argmax loop (aliases regM) ========
        const int BMW = (NN + 31) / 32;
        for (int i = tid; i < BMW; i += NT) bm[i] = 0u;
        __syncthreads();
        if (full_fb) {
            n_acc = 0;
        } else {
            for (int n = tid; n < NN; n += NT) {
                float4 bbn = bx4[n];
                float nb_area = __fmul_rn(__fsub_rn(bbn.z, bbn.x), __fsub_rn(bbn.w, bbn.y));
                int s = 0;
                for (int t = 0; t < n_acc; ++t) {
                    float4 A = abox[t];
                    if (iou_gt(A.x, A.y, A.z, A.w, aarea[t],
                               bbn.x, bbn.y, bbn.z, bbn.w, nb_area)) s = 1;
                }
                if (s) atomicOr(&bm[n >> 5], 1u << (n & 31));
            }
        }
        __syncthreads();

        for (int k = n_acc; k < MAX_DET; ++k) {
            float bv = neg_inf(); int bi = 0x7fffffff;
            for (int n = tid; n < NN; n += NT) {
                if (!((bm[n >> 5] >> (n & 31)) & 1u)) {
                    float v = sr[(size_t)n * NC];
                    if (v > SCORE_T && v > bv) { bv = v; bi = n; }
                }
            }
            rv[tid] = bv; ri[tid] = bi;
            __syncthreads();
            for (int s = NT / 2; s > 0; s >>= 1) {
                if (tid < s) {
                    float ov = rv[tid + s]; int oi = ri[tid + s];
                    if (ov > rv[tid] || (ov == rv[tid] && oi < ri[tid])) { rv[tid] = ov; ri[tid] = oi; }
                }
                __syncthreads();
            }
            float mval = rv[0]; int midx = ri[0];
            if (mval == neg_inf()) {
                for (int kk = k + tid; kk < MAX_DET; kk += NT) { si[kk] = 0; ss[kk] = neg_inf(); }
                break;
            }
            if (tid == 0) {
                si[k] = midx; ss[k] = mval;
                float4 sb = bx4[midx];
                sboxsh[0] = sb.x; sboxsh[1] = sb.y; sboxsh[2] = sb.z; sboxsh[3] = sb.w;
                sboxsh[4] = __fmul_rn(__fsub_rn(sb.z, sb.x), __fsub_rn(sb.w, sb.y));
            }
            __syncthreads();
            float ax1 = sboxsh[0], ay1 = sboxsh[1], ax2 = sboxsh[2], ay2 = sboxsh[3];
            float area_a = sboxsh[4];
            for (int n = tid; n < NN; n += NT) {
                float4 bbn = bx4[n];
                float nb_area = __fmul_rn(__fsub_rn(bbn.z, bbn.x), __fsub_rn(bbn.w, bbn.y));
                if (iou_gt(ax1, ay1, ax2, ay2, area_a,
                           bbn.x, bbn.y, bbn.z, bbn.w, nb_area))
                    atomicOr(&bm[n >> 5], 1u << (n & 31));
            }
            __syncthreads();
        }
    }
    // n_acc >= 300 without fallback: all 300 slots written in rank phase.
}

// ---------------- K3: top-300 via interleaved 8-way rank-selection --------
__global__ __launch_bounds__(1024) void topk_kernel(
    const float* __restrict__ boxes, const float* __restrict__ other,
    const int* __restrict__ sel_idx, const float* __restrict__ sel_score,
    float* __restrict__ out)
{
    const int b = blockIdx.x;
    const int tid = threadIdx.x;
    const int NCAND = NC * MAX_DET;        // 2400
    __shared__ u64 lists[NC][MAX_DET];

    for (int i = tid; i < NCAND; i += 1024) {
        float v = sel_score[b * NCAND + i];
        unsigned u = __float_as_uint(v);
        u ^= (u & 0x80000000u) ? 0xFFFFFFFFu : 0x80000000u;
        lists[i / MAX_DET][i % MAX_DET] = ((u64)u << 32) | (unsigned)(~(unsigned)i);
    }
    __syncthreads();

    const float4* bx4 = (const float4*)(boxes + (size_t)b * NN * 4);
    const float*  ot  = other + (size_t)b * NN * ND;
    float* ob = out;
    float* os = out + NB * MAX_DET * 4;
    float* ol = os + NB * MAX_DET;
    float* oo = ol + NB * MAX_DET;

    for (int i = tid; i < NCAND; i += 1024) {
        int cown = i / MAX_DET, slot = i - cown * MAX_DET;
        u64 K = lists[cown][slot];
        int rank = slot;
        int pos[NC], len[NC];
        #pragma unroll
        for (int c2 = 0; c2 < NC; ++c2) {
            pos[c2] = 0;
            len[c2] = (c2 == cown) ? 0 : MAX_DET;
        }
        for (int step = 0; step < 10; ++step) {
            #pragma unroll
            for (int c2 = 0; c2 < NC; ++c2) {
                if (len[c2] > 0) {
                    int half = len[c2] >> 1;
                    bool go = lists[c2][pos[c2] + half] > K;
                    pos[c2] = go ? pos[c2] + half + 1 : pos[c2];
                    len[c2] = go ? len[c2] - half - 1 : half;
                }
            }
        }
        #pragma unroll
        for (int c2 = 0; c2 < NC; ++c2) rank += pos[c2];

        if (rank < MAX_DET) {
            unsigned u = (unsigned)(K >> 32);
            unsigned uo = (u & 0x80000000u) ? (u ^ 0x80000000u) : (u ^ 0xFFFFFFFFu);
            float score = __uint_as_float(uo);
            bool valid = isfinite(score);
            float b0=-1.f,b1=-1.f,b2=-1.f,b3=-1.f,scv=-1.f,lab=-1.f,o0=-1.f,o1=-1.f;
            if (valid) {
                int n = sel_idx[b * NCAND + i];
                float4 bb = bx4[n];
                b0 = bb.x; b1 = bb.y; b2 = bb.z; b3 = bb.w;
                scv = score; lab = (float)cown;
                o0 = ot[n * ND + 0]; o1 = ot[n * ND + 1];
            }
            int base = b * MAX_DET + rank;
            ob[base * 4 + 0] = b0; ob[base * 4 + 1] = b1;
            ob[base * 4 + 2] = b2; ob[base * 4 + 3] = b3;
            os[base] = scv; ol[base] = lab;
            oo[base * 2 + 0] = o0; oo[base * 2 + 1] = o1;
        }
    }
}

extern "C" void kernel_launch(void* const* d_in, const int* in_sizes, int n_in,
                              void* d_out, int out_size, void* d_ws, size_t ws_size,
                              hipStream_t stream) {
    const float* boxes = (const float*)d_in[0];
    const float* cls   = (const float*)d_in[1];
    const float* other = (const float*)d_in[2];
    float* out = (float*)d_out;

    // ws: tcnt[4096] i32 | cand[128*32*LBUF] u64 | sel_idx | sel_score
    int* tcnt_g = (int*)d_ws;
    u64* cand  = (u64*)(tcnt_g + NB * NC * NTILE32);
    int* sel_idx = (int*)(cand + (size_t)NB * NC * NTILE32 * LBUF);
    float* sel_score = (float*)(sel_idx + NB * NC * MAX_DET);

    compact_kernel<<<NB * NTILE32, 1024, 0, stream>>>(cls, tcnt_g, cand);
    nms_fused<<<NB * NC, NT, 0, stream>>>(boxes, cls, cand, tcnt_g,
                                          sel_idx, sel_score);
    topk_kernel<<<NB, 1024, 0, stream>>>(boxes, other, sel_idx, sel_score, out);
}

// Round 19
// 64.410 us; speedup vs baseline: 1.3053x; 1.0606x over previous
//
#include <hip/hip_runtime.h>
#include <math.h>
#include <stdint.h>

#define NB 16
#define NN 50000
#define NC 8
#define ND 2
#define MAX_DET 300
#define NMS_T 0.5f
#define SCORE_T 0.05f
#define CAP 1024
#define CUTBIN 252        // s >= 0.984375 ; E[cnt]=781 +- 28
#define LBUF 128          // per-(class,tile) segment; E=24.4, +20 sigma
#define NTILE32 32
#define CHUNK 256
#define NT 1024
#define NPI (NN * NC)
#define F4PB (NPI / 4 / NTILE32)

typedef unsigned long long u64;

__device__ __forceinline__ float neg_inf() { return -__builtin_inff(); }

// Bit-exact IoU > 0.5, division-free (R11-validated). area_b passed in —
// computed with the identical _rn formula, so bits match the reference.
__device__ __forceinline__ bool iou_gt(float ax1, float ay1, float ax2, float ay2,
                                       float area_a,
                                       float bx1, float by1, float bx2, float by2,
                                       float area_b) {
    float x1 = fmaxf(ax1, bx1), y1 = fmaxf(ay1, by1);
    float x2 = fminf(ax2, bx2), y2 = fminf(ay2, by2);
    float inter = __fmul_rn(fmaxf(__fsub_rn(x2, x1), 0.0f),
                            fmaxf(__fsub_rn(y2, y1), 0.0f));
    float uni = __fsub_rn(__fadd_rn(area_a, area_b), inter);
    return inter > __fmul_rn(0.5f, fmaxf(uni, 1e-8f));
}

__device__ __forceinline__ u64 score_key(float s, int n) {
    unsigned u = __float_as_uint(s);
    u ^= (u & 0x80000000u) ? 0xFFFFFFFFu : 0x80000000u;
    return ((u64)u << 32) | (unsigned)(~(unsigned)n);
}

__device__ __forceinline__ u64 shfl_xor_u64(u64 v, int m) {
    unsigned lo = (unsigned)v, hi = (unsigned)(v >> 32);
    lo = __shfl_xor(lo, m, 64);
    hi = __shfl_xor(hi, m, 64);
    return ((u64)hi << 32) | lo;
}

// ---------------- C: tiled compaction, NO global atomics ------------------
__global__ __launch_bounds__(1024) void compact_kernel(
    const float* __restrict__ cls, int* __restrict__ tcnt_g,
    u64* __restrict__ cand)
{
    const int b = blockIdx.x >> 5, t32 = blockIdx.x & 31;
    const int tid = threadIdx.x;
    __shared__ u64 buf[8][LBUF];
    __shared__ int lcnt[8];
    if (tid < 8) lcnt[tid] = 0;
    __syncthreads();

    const float4* c4 = (const float4*)(cls + (size_t)b * NPI);
    const int f0 = t32 * F4PB, fend = f0 + F4PB;

    for (int f = f0 + tid; f < fend; f += 1024) {
        float4 v = c4[f];
        int cb = (f & 1) * 4;
        int n = f >> 1;
        float vv[4] = {v.x, v.y, v.z, v.w};
        #pragma unroll
        for (int k = 0; k < 4; ++k) {
            float s = vv[k];
            if (s > SCORE_T) {
                int bn = (int)(s * 256.0f); if (bn > 255) bn = 255;
                if (bn >= CUTBIN) {
                    int c = cb + k;
                    int pos = atomicAdd(&lcnt[c], 1);   // LDS only
                    if (pos < LBUF) buf[c][pos] = score_key(s, n);
                }
            }
        }
    }
    __syncthreads();
    {
        int c = tid >> 7, i = tid & (LBUF - 1);
        int m = lcnt[c];
        if (i < (m < LBUF ? m : LBUF))
            cand[(size_t)(((b * 8 + c) * NTILE32) + t32) * LBUF + i] = buf[c][i];
        if (i == 0) tcnt_g[(b * 8 + c) * NTILE32 + t32] = m;
    }
}

// ---------------- N: fused gather + sort + 256-chunk fixpoint greedy ------
__global__ __launch_bounds__(NT) void nms_fused(
    const float* __restrict__ boxes, const float* __restrict__ cls,
    const u64* __restrict__ cand, const int* __restrict__ tcnt_g,
    int* __restrict__ sel_idx, float* __restrict__ sel_score)
{
    const int bc = blockIdx.x;
    const int b = bc >> 3, c = bc & 7;
    const int tid = threadIdx.x;
    const int lane = tid & 63;
    const float4* bx4 = (const float4*)(boxes + (size_t)b * NN * 4);
    const float* sr = cls + (size_t)b * NN * NC + c;   // fallback only
    int* si = sel_idx + bc * MAX_DET;
    float* ss = sel_score + bc * MAX_DET;

    __shared__ u64 keys[CAP];                    // 8 KB
    __shared__ int tcnt_s[NTILE32], toff_s[NTILE32];
    __shared__ int sh_total, sh_ovf;
    __shared__ u64 M64[4][CHUNK];                // 8 KB lower-triangle rows
    __shared__ unsigned presup4[4][CHUNK];       // 4 KB
    __shared__ float4 cbox2[2][CHUNK];           // 8 KB
    __shared__ float  carea2[2][CHUNK];          // 2 KB
    __shared__ int    cidx2[2][CHUNK];           // 2 KB
    __shared__ float  cscore2[2][CHUNK];         // 2 KB
    __shared__ u64 accs4_s[4];
    __shared__ float4 abox[MAX_DET];             // 4.8 KB
    __shared__ float aarea[MAX_DET];             // 1.2 KB
    __shared__ unsigned bm[(NN + 31) / 32];      // 6.3 KB fallback bitmask
    __shared__ float rv[NT];                     // 4 KB
    __shared__ int   ri[NT];                     // 4 KB
    __shared__ float sboxsh[5];

    // ---- tile-count scan (wave 0) ----
    if (tid < 64) {
        int v = (lane < NTILE32) ? tcnt_g[bc * NTILE32 + lane] : 0;
        int incl = v;
        #pragma unroll
        for (int d = 1; d < 32; d <<= 1) {
            int o = __shfl_up(incl, d, 64);
            if (lane >= d) incl += o;
        }
        if (lane < NTILE32) { tcnt_s[lane] = v; toff_s[lane] = incl - v; }
        u64 ov = __ballot(lane < NTILE32 && v > LBUF);
        if (lane == 31) { sh_total = incl; sh_ovf = (ov != 0); }
    }
    __syncthreads();
    const int cnt = sh_total;
    const bool full_fb = sh_ovf || (cnt > CAP);
    const int inSet = cnt < CAP ? cnt : CAP;

    int n_acc = 0;
    if (!full_fb) {
        // ---- zero + flat gather into keys ----
        for (int i = tid; i < CAP; i += NT) keys[i] = 0ull;
        __syncthreads();
        for (int s = tid; s < NTILE32 * LBUF; s += NT) {
            int t = s >> 7, i = s & (LBUF - 1);
            if (i < tcnt_s[t])
                keys[toff_s[t] + i] = cand[(size_t)(bc * NTILE32 + t) * LBUF + i];
        }
        __syncthreads();

        // ===== hybrid reg/LDS bitonic sort (threads 0-511 own 2 keys) =====
        const int p0 = (tid >> 6) * 128 + lane, p1 = p0 + 64;
        u64 v0 = 0, v1 = 0;
        if (tid < 512) {
            v0 = keys[p0]; v1 = keys[p1];
            #pragma unroll
            for (int k = 2; k <= 128; k <<= 1) {
                #pragma unroll
                for (int j = k >> 1; j > 0; j >>= 1) {
                    if (j == 64) {
                        bool dir = ((p0 & k) == 0);
                        if ((v0 < v1) == dir) { u64 t = v0; v0 = v1; v1 = t; }
                    } else {
                        bool lower = ((lane & j) == 0);
                        bool dir0 = ((p0 & k) == 0);
                        bool dir1 = ((p1 & k) == 0);   // differs at k=64
                        u64 o0 = shfl_xor_u64(v0, j);
                        u64 mx0 = v0 > o0 ? v0 : o0, mn0 = v0 > o0 ? o0 : v0;
                        v0 = (lower == dir0) ? mx0 : mn0;
                        u64 o1 = shfl_xor_u64(v1, j);
                        u64 mx1 = v1 > o1 ? v1 : o1, mn1 = v1 > o1 ? o1 : v1;
                        v1 = (lower == dir1) ? mx1 : mn1;
                    }
                }
            }
        }
        __syncthreads();
        for (int k = 256; k <= CAP; k <<= 1) {
            if (tid < 512) { keys[p0] = v0; keys[p1] = v1; }
            __syncthreads();
            for (int j = k >> 1; j >= 128; j >>= 1) {
                if (tid < 512) {
                    int p = tid;
                    int i = 2 * p - (p & (j - 1));
                    int ix = i + j;
                    bool dir = ((i & k) == 0);
                    u64 a = keys[i], b2 = keys[ix];
                    if ((a < b2) == dir) { keys[i] = b2; keys[ix] = a; }
                }
                __syncthreads();
            }
            if (tid < 512) {
                v0 = keys[p0]; v1 = keys[p1];
                {
                    bool dir = ((p0 & k) == 0);
                    if ((v0 < v1) == dir) { u64 t = v0; v0 = v1; v1 = t; }
                }
                #pragma unroll
                for (int j = 32; j > 0; j >>= 1) {   // k>=256: (p1&k)==(p0&k)
                    bool lower = ((lane & j) == 0);
                    bool dir = ((p0 & k) == 0);
                    u64 o0 = shfl_xor_u64(v0, j);
                    u64 mx0 = v0 > o0 ? v0 : o0, mn0 = v0 > o0 ? o0 : v0;
                    v0 = (lower == dir) ? mx0 : mn0;
                    u64 o1 = shfl_xor_u64(v1, j);
                    u64 mx1 = v1 > o1 ? v1 : o1, mn1 = v1 > o1 ? o1 : v1;
                    v1 = (lower == dir) ? mx1 : mn1;
                }
            }
            __syncthreads();
        }
        if (tid < 512) { keys[p0] = v0; keys[p1] = v1; }
        __syncthreads();

        // ===== stage chunk 0 =====
        if (tid < CHUNK && tid < inSet) {
            u64 key = keys[tid];
            int idx = (int)(~(unsigned)key);
            unsigned u = (unsigned)(key >> 32);
            unsigned uo = (u & 0x80000000u) ? (u ^ 0x80000000u) : (~u);
            float4 bb = bx4[idx];
            cbox2[0][tid] = bb;
            carea2[0][tid] = __fmul_rn(__fsub_rn(bb.z, bb.x), __fsub_rn(bb.w, bb.y));
            cidx2[0][tid] = idx; cscore2[0][tid] = __uint_as_float(uo);
        }
        __syncthreads();

        int base = 0, cur = 0;
        while (n_acc < MAX_DET && base < inSet) {
            int m = inSet - base; if (m > CHUNK) m = CHUNK;

            // ---- phase A: presup (x8 batch) + 64-wide triangle segment ----
            {
                int i = tid & (CHUNK - 1);
                int q = tid >> 8;                    // 0..3
                if (i < m) {
                    float4 B = cbox2[cur][i];
                    float  Barea = carea2[cur][i];
                    unsigned p = 0;
                    int t = q;
                    for (; t + 28 < n_acc; t += 32) {
                        float4 A0 = abox[t];      float r0 = aarea[t];
                        float4 A1 = abox[t + 4];  float r1 = aarea[t + 4];
                        float4 A2 = abox[t + 8];  float r2 = aarea[t + 8];
                        float4 A3 = abox[t + 12]; float r3 = aarea[t + 12];
                        float4 A4 = abox[t + 16]; float r4 = aarea[t + 16];
                        float4 A5 = abox[t + 20]; float r5 = aarea[t + 20];
                        float4 A6 = abox[t + 24]; float r6 = aarea[t + 24];
                        float4 A7 = abox[t + 28]; float r7 = aarea[t + 28];
                        bool s0 = iou_gt(A0.x,A0.y,A0.z,A0.w,r0,B.x,B.y,B.z,B.w,Barea);
                        bool s1 = iou_gt(A1.x,A1.y,A1.z,A1.w,r1,B.x,B.y,B.z,B.w,Barea);
                        bool s2 = iou_gt(A2.x,A2.y,A2.z,A2.w,r2,B.x,B.y,B.z,B.w,Barea);
                        bool s3 = iou_gt(A3.x,A3.y,A3.z,A3.w,r3,B.x,B.y,B.z,B.w,Barea);
                        bool s4 = iou_gt(A4.x,A4.y,A4.z,A4.w,r4,B.x,B.y,B.z,B.w,Barea);
                        bool s5 = iou_gt(A5.x,A5.y,A5.z,A5.w,r5,B.x,B.y,B.z,B.w,Barea);
                        bool s6 = iou_gt(A6.x,A6.y,A6.z,A6.w,r6,B.x,B.y,B.z,B.w,Barea);
                        bool s7 = iou_gt(A7.x,A7.y,A7.z,A7.w,r7,B.x,B.y,B.z,B.w,Barea);
                        if (s0|s1|s2|s3|s4|s5|s6|s7) { p = 1; break; }
                    }
                    if (!p) {
                        for (; t < n_acc; t += 4) {
                            float4 A = abox[t];
                            if (iou_gt(A.x,A.y,A.z,A.w,aarea[t],
                                       B.x,B.y,B.z,B.w,Barea)) { p = 1; break; }
                        }
                    }
                    presup4[q][i] = p;
                    // triangle segment: j in [64q, 64q+64) ∩ [0, i)
                    u64 bits = 0;
                    int j0 = q * 64;
                    int jend = i - j0; if (jend > 64) jend = 64; if (jend < 0) jend = 0;
                    int jj = 0;
                    for (; jj + 7 < jend; jj += 8) {
                        int j = j0 + jj;
                        float4 A0 = cbox2[cur][j];     float r0 = carea2[cur][j];
                        float4 A1 = cbox2[cur][j + 1]; float r1 = carea2[cur][j + 1];
                        float4 A2 = cbox2[cur][j + 2]; float r2 = carea2[cur][j + 2];
                        float4 A3 = cbox2[cur][j + 3]; float r3 = carea2[cur][j + 3];
                        float4 A4 = cbox2[cur][j + 4]; float r4 = carea2[cur][j + 4];
                        float4 A5 = cbox2[cur][j + 5]; float r5 = carea2[cur][j + 5];
                        float4 A6 = cbox2[cur][j + 6]; float r6 = carea2[cur][j + 6];
                        float4 A7 = cbox2[cur][j + 7]; float r7 = carea2[cur][j + 7];
                        if (iou_gt(A0.x,A0.y,A0.z,A0.w,r0,B.x,B.y,B.z,B.w,Barea)) bits |= 1ull << jj;
                        if (iou_gt(A1.x,A1.y,A1.z,A1.w,r1,B.x,B.y,B.z,B.w,Barea)) bits |= 1ull << (jj+1);
                        if (iou_gt(A2.x,A2.y,A2.z,A2.w,r2,B.x,B.y,B.z,B.w,Barea)) bits |= 1ull << (jj+2);
                        if (iou_gt(A3.x,A3.y,A3.z,A3.w,r3,B.x,B.y,B.z,B.w,Barea)) bits |= 1ull << (jj+3);
                        if (iou_gt(A4.x,A4.y,A4.z,A4.w,r4,B.x,B.y,B.z,B.w,Barea)) bits |= 1ull << (jj+4);
                        if (iou_gt(A5.x,A5.y,A5.z,A5.w,r5,B.x,B.y,B.z,B.w,Barea)) bits |= 1ull << (jj+5);
                        if (iou_gt(A6.x,A6.y,A6.z,A6.w,r6,B.x,B.y,B.z,B.w,Barea)) bits |= 1ull << (jj+6);
                        if (iou_gt(A7.x,A7.y,A7.z,A7.w,r7,B.x,B.y,B.z,B.w,Barea)) bits |= 1ull << (jj+7);
                    }
                    for (; jj < jend; ++jj) {
                        int j = j0 + jj;
                        float4 A = cbox2[cur][j];
                        if (iou_gt(A.x,A.y,A.z,A.w,carea2[cur][j],
                                   B.x,B.y,B.z,B.w,Barea)) bits |= 1ull << jj;
                    }
                    M64[q][i] = bits;
                }
            }
            __syncthreads();

            // ---- phase B: wave-0 fixpoint resolve ∥ waves 4-7 gather next ----
            int nbase = base + m;
            if (tid < 64) {
                u64 Mr[4][4];
                unsigned pe[4];
                bool acc[4];
                #pragma unroll
                for (int cg = 0; cg < 4; ++cg) {
                    int i = cg * 64 + lane;
                    if (i < m) {
                        pe[cg] = presup4[0][i] | presup4[1][i] | presup4[2][i] | presup4[3][i];
                        #pragma unroll
                        for (int w = 0; w < 4; ++w) Mr[cg][w] = M64[w][i];
                    } else {
                        pe[cg] = 1u;
                        #pragma unroll
                        for (int w = 0; w < 4; ++w) Mr[cg][w] = 0ull;
                    }
                    acc[cg] = (pe[cg] == 0);
                }
                u64 a0 = __ballot(acc[0]), a1 = __ballot(acc[1]);
                u64 a2 = __ballot(acc[2]), a3 = __ballot(acc[3]);
                // Jacobi fixpoint: unique fixpoint == greedy; converges in <= m iters
                for (int it = 0; it < CHUNK + 1; ++it) {
                    #pragma unroll
                    for (int cg = 0; cg < 4; ++cg) {
                        u64 sup = (Mr[cg][0] & a0) | (Mr[cg][1] & a1)
                                | (Mr[cg][2] & a2) | (Mr[cg][3] & a3);
                        acc[cg] = (pe[cg] == 0) && (sup == 0ull);
                    }
                    u64 n0 = __ballot(acc[0]), n1 = __ballot(acc[1]);
                    u64 n2 = __ballot(acc[2]), n3 = __ballot(acc[3]);
                    bool same = (n0 == a0) && (n1 == a1) && (n2 == a2) && (n3 == a3);
                    a0 = n0; a1 = n1; a2 = n2; a3 = n3;
                    if (same) break;
                }
                if (lane == 0) { accs4_s[0] = a0; accs4_s[1] = a1;
                                 accs4_s[2] = a2; accs4_s[3] = a3; }
            } else if (tid >= 256 && tid < 512 && nbase < inSet) {
                int w = tid - 256;
                if (nbase + w < inSet) {
                    u64 key = keys[nbase + w];
                    int idx = (int)(~(unsigned)key);
                    unsigned u = (unsigned)(key >> 32);
                    unsigned uo = (u & 0x80000000u) ? (u ^ 0x80000000u) : (~u);
                    float4 bb = bx4[idx];
                    cbox2[cur ^ 1][w] = bb;
                    carea2[cur ^ 1][w] = __fmul_rn(__fsub_rn(bb.z, bb.x), __fsub_rn(bb.w, bb.y));
                    cidx2[cur ^ 1][w] = idx; cscore2[cur ^ 1][w] = __uint_as_float(uo);
                }
            }
            __syncthreads();

            // ---- phase C: rank + write accepted (cap 300) ----
            u64 a0 = accs4_s[0], a1 = accs4_s[1], a2 = accs4_s[2], a3 = accs4_s[3];
            int add = __popcll(a0) + __popcll(a1) + __popcll(a2) + __popcll(a3);
            if (tid < m) {
                int gg = tid >> 6, o = tid & 63;
                u64 aw = (gg == 0) ? a0 : (gg == 1) ? a1 : (gg == 2) ? a2 : a3;
                if ((aw >> o) & 1ull) {
                    int rank = 0;
                    if (gg > 0) rank += __popcll(a0);
                    if (gg > 1) rank += __popcll(a1);
                    if (gg > 2) rank += __popcll(a2);
                    rank += __popcll(aw & ((1ull << o) - 1ull));
                    int pos = n_acc + rank;
                    if (pos < MAX_DET) {
                        abox[pos] = cbox2[cur][tid]; aarea[pos] = carea2[cur][tid];
                        si[pos] = cidx2[cur][tid]; ss[pos] = cscore2[cur][tid];
                    }
                }
            }
            n_acc += add; if (n_acc > MAX_DET) n_acc = MAX_DET;
            base = nbase; cur ^= 1;
            __syncthreads();
        }
    }

    const bool part_fb = (!full_fb) && (n_acc < MAX_DET);

    if (full_fb || part_fb) {
        // ======== exact fallback: bitmask argmax loop ========
        const int BMW = (NN + 31) / 32;
        for (int i = tid; i < BMW; i += NT) bm[i] = 0u;
        __syncthreads();
        if (full_fb) {
            n_acc = 0;
        } else {
            for (int n = tid; n < NN; n += NT) {
                float4 bbn = bx4[n];
                float nb_area = __fmul_rn(__fsub_rn(bbn.z, bbn.x), __fsub_rn(bbn.w, bbn.y));
                int s = 0;
                for (int t = 0; t < n_acc; ++t) {
                    float4 A = abox[t];
                    if (iou_gt(A.x, A.y, A.z, A.w, aarea[t],
                               bbn.x, bbn.y, bbn.z, bbn.w, nb_area)) s = 1;
                }
                if (s) atomicOr(&bm[n >> 5], 1u << (n & 31));
            }
        }
        __syncthreads();

        for (int k = n_acc; k < MAX_DET; ++k) {
            float bv = neg_inf(); int bi = 0x7fffffff;
            for (int n = tid; n < NN; n += NT) {
                if (!((bm[n >> 5] >> (n & 31)) & 1u)) {
                    float v = sr[(size_t)n * NC];
                    if (v > SCORE_T && v > bv) { bv = v; bi = n; }
                }
            }
            rv[tid] = bv; ri[tid] = bi;
            __syncthreads();
            for (int s = NT / 2; s > 0; s >>= 1) {
                if (tid < s) {
                    float ov = rv[tid + s]; int oi = ri[tid + s];
                    if (ov > rv[tid] || (ov == rv[tid] && oi < ri[tid])) { rv[tid] = ov; ri[tid] = oi; }
                }
                __syncthreads();
            }
            float mval = rv[0]; int midx = ri[0];
            if (mval == neg_inf()) {
                for (int kk = k + tid; kk < MAX_DET; kk += NT) { si[kk] = 0; ss[kk] = neg_inf(); }
                break;
            }
            if (tid == 0) {
                si[k] = midx; ss[k] = mval;
                float4 sb = bx4[midx];
                sboxsh[0] = sb.x; sboxsh[1] = sb.y; sboxsh[2] = sb.z; sboxsh[3] = sb.w;
                sboxsh[4] = __fmul_rn(__fsub_rn(sb.z, sb.x), __fsub_rn(sb.w, sb.y));
            }
            __syncthreads();
            float ax1 = sboxsh[0], ay1 = sboxsh[1], ax2 = sboxsh[2], ay2 = sboxsh[3];
            float area_a = sboxsh[4];
            for (int n = tid; n < NN; n += NT) {
                float4 bbn = bx4[n];
                float nb_area = __fmul_rn(__fsub_rn(bbn.z, bbn.x), __fsub_rn(bbn.w, bbn.y));
                if (iou_gt(ax1, ay1, ax2, ay2, area_a,
                           bbn.x, bbn.y, bbn.z, bbn.w, nb_area))
                    atomicOr(&bm[n >> 5], 1u << (n & 31));
            }
            __syncthreads();
        }
    } else {
        for (int kk = n_acc + tid; kk < MAX_DET; kk += NT) { si[kk] = 0; ss[kk] = neg_inf(); }
    }
}

// ---------------- T: top-300 via 8-way merge of sorted class lists --------
__global__ __launch_bounds__(1024) void topk_kernel(
    const float* __restrict__ boxes, const float* __restrict__ other,
    const int* __restrict__ sel_idx, const float* __restrict__ sel_score,
    float* __restrict__ out)
{
    const int b = blockIdx.x;
    const int tid = threadIdx.x;
    __shared__ u64 keys[4096];

    for (int i = tid; i < 4096; i += 1024) {
        int c = i >> 9, o = i & 511;
        u64 key = 0ull;
        if (o < MAX_DET) {
            int m = c * MAX_DET + o;
            float v = sel_score[b * NC * MAX_DET + m];
            unsigned u = __float_as_uint(v);
            u ^= (u & 0x80000000u) ? 0xFFFFFFFFu : 0x80000000u;
            key = ((u64)u << 32) | (unsigned)(~(unsigned)m);
        }
        keys[i] = key;
    }

    for (int seg = 1024; seg <= 4096; seg <<= 1) {
        int half = seg >> 1;
        __syncthreads();
        {
            int p = tid;
            int s = p / (half >> 1), t = p % (half >> 1);
            int i0 = s * seg + half + t;
            int i1 = s * seg + seg - 1 - t;
            u64 a = keys[i0]; keys[i0] = keys[i1]; keys[i1] = a;
        }
        __syncthreads();
        for (int j = half; j > 0; j >>= 1) {
            for (int p = tid; p < 2048; p += 1024) {
                int i = 2 * p - (p & (j - 1));
                int ix = i + j;
                u64 a = keys[i], bq = keys[ix];
                if (a < bq) { keys[i] = bq; keys[ix] = a; }
            }
            if (j >= 128) __syncthreads(); else __threadfence_block();
        }
    }
    __syncthreads();

    const float4* bx4 = (const float4*)(boxes + (size_t)b * NN * 4);
    const float*  ot  = other + (size_t)b * NN * ND;
    float* ob = out;
    float* os = out + NB * MAX_DET * 4;
    float* ol = os + NB * MAX_DET;
    float* oo = ol + NB * MAX_DET;

    for (int k = tid; k < MAX_DET; k += 1024) {
        u64 key = keys[k];
        unsigned u = (unsigned)(key >> 32);
        unsigned uo = (u & 0x80000000u) ? (u ^ 0x80000000u) : (u ^ 0xFFFFFFFFu);
        float score = __uint_as_float(uo);
        bool valid = isfinite(score);
        float b0=-1.f,b1=-1.f,b2=-1.f,b3=-1.f,scv=-1.f,lab=-1.f,o0=-1.f,o1=-1.f;
        if (valid) {
            int m = (int)(~(unsigned)key);
            int c = m / MAX_DET, slot = m - c * MAX_DET;
            int n = sel_idx[(b * NC + c) * MAX_DET + slot];
            float4 bb = bx4[n];
            b0 = bb.x; b1 = bb.y; b2 = bb.z; b3 = bb.w;
            scv = score; lab = (float)c;
            o0 = ot[n * ND + 0]; o1 = ot[n * ND + 1];
        }
        int base = b * MAX_DET + k;
        ob[base * 4 + 0] = b0; ob[base * 4 + 1] = b1;
        ob[base * 4 + 2] = b2; ob[base * 4 + 3] = b3;
        os[base] = scv; ol[base] = lab;
        oo[base * 2 + 0] = o0; oo[base * 2 + 1] = o1;
    }
}

extern "C" void kernel_launch(void* const* d_in, const int* in_sizes, int n_in,
                              void* d_out, int out_size, void* d_ws, size_t ws_size,
                              hipStream_t stream) {
    const float* boxes = (const float*)d_in[0];
    const float* cls   = (const float*)d_in[1];
    const float* other = (const float*)d_in[2];
    float* out = (float*)d_out;

    // ws: tcnt[128*32] | cand[128*32*LBUF] u64 | sel_idx | sel_score
    int* tcnt_g = (int*)d_ws;
    u64* cand  = (u64*)(tcnt_g + NB * NC * NTILE32);
    int* sel_idx = (int*)(cand + (size_t)NB * NC * NTILE32 * LBUF);
    float* sel_score = (float*)(sel_idx + NB * NC * MAX_DET);

    compact_kernel<<<NB * NTILE32, 1024, 0, stream>>>(cls, tcnt_g, cand);
    nms_fused<<<NB * NC, NT, 0, stream>>>(boxes, cls, cand, tcnt_g,
                                          sel_idx, sel_score);
    topk_kernel<<<NB, 1024, 0, stream>>>(boxes, other, sel_idx, sel_score, out);
}